// Round 1
// baseline (325.971 us; speedup 1.0000x reference)
//
#include <hip/hip_runtime.h>

// Problem constants
#define KC   1024        // codebook size
#define DD   64          // code dim
#define NR   65536       // total rows (16*4096)

#define DECAY     0.99f
#define ONEM      0.01f
#define EPSV      1e-5f

// d_out layout (floats), in reference return order:
//   z_q_out      [0,        4194304)
//   vq_loss      [4194304,  4194305)
//   indices_out  [4194305,  4325377-?) -> 65536
//   new_codebook [4259841,  4325377)
//   new_ecs      [4325377,  4326401)
//   new_ew       [4326401,  4391937)
#define OFF_ZQ    0
#define OFF_LOSS  4194304
#define OFF_IDX   4194305
#define OFF_NCB   4259841
#define OFF_NECS  4325377
#define OFF_NEW   4326401

// Scratch aliases inside d_out (zeroed by prep, consumed+overwritten by final):
//   cluster counts  -> OFF_NECS region (1024)
//   cluster sums    -> OFF_NEW region (65536)
//   sum-sq-error    -> OFF_LOSS (1)
//   ||c||^2 table   -> first 1024 floats of OFF_NCB region

__global__ void vq_prep(const float* __restrict__ cb, float* __restrict__ out) {
    int tid = blockIdx.x * blockDim.x + threadIdx.x;
    if (tid < 65536) out[OFF_NEW + tid] = 0.0f;          // cluster sums
    if (tid < 1024) {
        out[OFF_NECS + tid] = 0.0f;                      // cluster counts
        const float* c = cb + tid * 64;
        float s = 0.f;
        #pragma unroll
        for (int d = 0; d < 64; ++d) s += c[d] * c[d];
        out[OFF_NCB + tid] = s;                          // ||c_k||^2
    }
    if (tid == 0) out[OFF_LOSS] = 0.0f;                  // SSE accumulator
}

// 1024 blocks x 256 threads. Each block owns 64 rows.
// lane (0..63) = row within block tile; wave (0..3) = 256-code K-chunk.
// Codebook reads are wave-uniform -> scalar loads; VALU does only FMAs.
__global__ __launch_bounds__(256) void vq_main(const float* __restrict__ z,
                                               const float* __restrict__ cb,
                                               const float* __restrict__ cc,
                                               float* __restrict__ out) {
    const int lane = threadIdx.x & 63;
    const int wid  = threadIdx.x >> 6;
    const int row  = blockIdx.x * 64 + lane;

    // Load this lane's z row into registers (64 VGPRs).
    float zr[64];
    {
        const float4* zp = reinterpret_cast<const float4*>(z + (size_t)row * 64);
        #pragma unroll
        for (int j = 0; j < 16; ++j) {
            float4 v = zp[j];
            zr[4*j+0] = v.x; zr[4*j+1] = v.y; zr[4*j+2] = v.z; zr[4*j+3] = v.w;
        }
    }
    float zz = 0.f;
    #pragma unroll
    for (int d = 0; d < 64; ++d) zz = fmaf(zr[d], zr[d], zz);

    // Force wave-uniform chunk base into an SGPR so codebook reads are s_loads.
    const int kbase = __builtin_amdgcn_readfirstlane(wid) * 256;

    float bestd = 3.4e38f;
    int   bestk = kbase;
    for (int k0 = kbase; k0 < kbase + 256; k0 += 4) {
        const float* c0 = cb + (size_t)k0 * 64;
        float a0 = 0.f, a1 = 0.f, a2 = 0.f, a3 = 0.f;
        #pragma unroll
        for (int d = 0; d < 64; ++d) {
            const float zd = zr[d];
            a0 = fmaf(zd, c0[d      ], a0);
            a1 = fmaf(zd, c0[d +  64], a1);
            a2 = fmaf(zd, c0[d + 128], a2);
            a3 = fmaf(zd, c0[d + 192], a3);
        }
        const float d0 = zz + cc[k0    ] - 2.f * a0;
        const float d1 = zz + cc[k0 + 1] - 2.f * a1;
        const float d2 = zz + cc[k0 + 2] - 2.f * a2;
        const float d3 = zz + cc[k0 + 3] - 2.f * a3;
        if (d0 < bestd) { bestd = d0; bestk = k0;     }
        if (d1 < bestd) { bestd = d1; bestk = k0 + 1; }
        if (d2 < bestd) { bestd = d2; bestk = k0 + 2; }
        if (d3 < bestd) { bestd = d3; bestk = k0 + 3; }
    }

    __shared__ float s_dist[4][64];
    __shared__ int   s_idx [4][64];
    __shared__ int   s_final[64];
    s_dist[wid][lane] = bestd;
    s_idx [wid][lane] = bestk;
    __syncthreads();

    if (wid == 0) {
        float bd = s_dist[0][lane];
        int   bk = s_idx [0][lane];
        #pragma unroll
        for (int w = 1; w < 4; ++w) {
            const float dw = s_dist[w][lane];
            if (dw < bd) { bd = dw; bk = s_idx[w][lane]; }  // strict <: first-index tiebreak
        }
        s_final[lane] = bk;
        out[OFF_IDX + row] = (float)bk;
        atomicAdd(&out[OFF_NECS + bk], 1.0f);               // cluster count
    }
    __syncthreads();

    // Phase 2: coalesced z_q write + commitment SSE + cluster-sum atomics.
    // Block tile = 64 rows * 64 dims = 1024 float4s; thread t handles 4 of them.
    const int t = threadIdx.x;
    float sse = 0.f;
    const float4* zb = reinterpret_cast<const float4*>(z) + (size_t)blockIdx.x * 1024;
    float4*       qb = reinterpret_cast<float4*>(out + OFF_ZQ) + (size_t)blockIdx.x * 1024;
    const float4* cb4 = reinterpret_cast<const float4*>(cb);
    #pragma unroll
    for (int j = 0; j < 4; ++j) {
        const int f  = t + 256 * j;     // float4 index in block tile
        const int r  = f >> 4;          // row within tile
        const int fc = f & 15;          // float4 within row
        const int gk = s_final[r];
        const float4 zv = zb[f];
        const float4 cv = cb4[gk * 16 + fc];
        qb[f] = cv;                     // z_q_st == z_q numerically
        const float e0 = zv.x - cv.x, e1 = zv.y - cv.y;
        const float e2 = zv.z - cv.z, e3 = zv.w - cv.w;
        sse += e0*e0 + e1*e1 + e2*e2 + e3*e3;
        float* sp = out + OFF_NEW + gk * 64 + fc * 4;
        atomicAdd(sp + 0, zv.x);
        atomicAdd(sp + 1, zv.y);
        atomicAdd(sp + 2, zv.z);
        atomicAdd(sp + 3, zv.w);
    }

    __shared__ float s_red[256];
    s_red[t] = sse;
    __syncthreads();
    for (int off = 128; off > 0; off >>= 1) {
        if (t < off) s_red[t] += s_red[t + off];
        __syncthreads();
    }
    if (t == 0) atomicAdd(&out[OFF_LOSS], s_red[0]);
}

// One block, 1024 threads: EMA update + normalization + loss finalize.
__global__ __launch_bounds__(1024) void vq_final(const float* __restrict__ ema_cs,
                                                 const float* __restrict__ ema_w,
                                                 float* __restrict__ out) {
    const int k = threadIdx.x;
    const float cnt  = out[OFF_NECS + k];
    const float necs = DECAY * ema_cs[k] + ONEM * cnt;

    __shared__ float s_red[1024];
    __shared__ float s_den[1024];
    s_red[k] = necs;
    __syncthreads();
    for (int off = 512; off > 0; off >>= 1) {
        if (k < off) s_red[k] += s_red[k + off];
        __syncthreads();
    }
    const float n = s_red[0];

    out[OFF_NECS + k] = necs;
    s_den[k] = (necs + EPSV) / (n + (float)KC * EPSV) * n;
    __syncthreads();

    #pragma unroll 4
    for (int i = 0; i < 64; ++i) {
        const int e = k + 1024 * i;             // coalesced over 65536 elements
        const float s  = out[OFF_NEW + e];      // raw cluster sum
        const float ew = DECAY * ema_w[e] + ONEM * s;
        out[OFF_NEW + e] = ew;                  // new_ew
        out[OFF_NCB + e] = ew / s_den[e >> 6];  // new_codebook
    }
    if (k == 0) out[OFF_LOSS] = 0.25f * out[OFF_LOSS] * (1.f / 4194304.f);
}

extern "C" void kernel_launch(void* const* d_in, const int* in_sizes, int n_in,
                              void* d_out, int out_size, void* d_ws, size_t ws_size,
                              hipStream_t stream) {
    const float* z   = (const float*)d_in[0];
    const float* cb  = (const float*)d_in[1];
    const float* ecs = (const float*)d_in[2];
    const float* ew  = (const float*)d_in[3];
    float* out = (float*)d_out;

    vq_prep <<<256,  256, 0, stream>>>(cb, out);
    vq_main <<<1024, 256, 0, stream>>>(z, cb, out + OFF_NCB, out);
    vq_final<<<1,   1024, 0, stream>>>(ecs, ew, out);
}

// Round 2
// 315.917 us; speedup vs baseline: 1.0318x; 1.0318x over previous
//
#include <hip/hip_runtime.h>

// Problem constants
#define KC   1024        // codebook size
#define DD   64          // code dim
#define NR   65536       // total rows (16*4096)

#define DECAY     0.99f
#define ONEM      0.01f
#define EPSV      1e-5f

// d_out layout (floats), in reference return order:
#define OFF_ZQ    0
#define OFF_LOSS  4194304
#define OFF_IDX   4194305
#define OFF_NCB   4259841
#define OFF_NECS  4325377
#define OFF_NEW   4326401

// Scratch aliases inside d_out (zeroed by prep, consumed+overwritten by final):
//   cluster counts  -> OFF_NECS region (1024)
//   cluster sums    -> OFF_NEW region (65536)
//   sum-sq-error    -> OFF_LOSS (1)
//   ||c||^2 table   -> first 1024 floats of OFF_NCB region

__global__ void vq_prep(const float* __restrict__ cb, float* __restrict__ out) {
    int tid = blockIdx.x * blockDim.x + threadIdx.x;
    if (tid < 65536) out[OFF_NEW + tid] = 0.0f;          // cluster sums
    if (tid < 1024) {
        out[OFF_NECS + tid] = 0.0f;                      // cluster counts
        const float* c = cb + tid * 64;
        float s = 0.f;
        #pragma unroll
        for (int d = 0; d < 64; ++d) s += c[d] * c[d];
        out[OFF_NCB + tid] = s;                          // ||c_k||^2
    }
    if (tid == 0) out[OFF_LOSS] = 0.0f;                  // SSE accumulator
}

// 1024 blocks x 512 threads (8 waves). Each block owns 64 rows.
// lane (0..63) = row within block tile; wave (0..7) = 128-code K-chunk.
// Codebook addresses are wave-uniform -> L1 broadcast loads.
__global__ __launch_bounds__(512, 2) void vq_main(const float* __restrict__ z,
                                                  const float* __restrict__ cb,
                                                  const float* __restrict__ cc,
                                                  float* __restrict__ out) {
    const int lane = threadIdx.x & 63;
    const int wid  = threadIdx.x >> 6;
    const int row  = blockIdx.x * 64 + lane;

    // Load this lane's z row into registers (64 VGPRs as 16 float4s).
    float4 zr[16];
    {
        const float4* zp = reinterpret_cast<const float4*>(z + (size_t)row * 64);
        #pragma unroll
        for (int j = 0; j < 16; ++j) zr[j] = zp[j];
    }
    float zz = 0.f;
    #pragma unroll
    for (int j = 0; j < 16; ++j) {
        zz = fmaf(zr[j].x, zr[j].x, zz);
        zz = fmaf(zr[j].y, zr[j].y, zz);
        zz = fmaf(zr[j].z, zr[j].z, zz);
        zz = fmaf(zr[j].w, zr[j].w, zz);
    }

    // Wave-uniform chunk base in an SGPR.
    const int kbase = __builtin_amdgcn_readfirstlane(wid) * 128;

    float bestd = 3.4e38f;
    int   bestk = kbase;
    for (int k0 = kbase; k0 < kbase + 128; k0 += 4) {
        const float4* c4 = reinterpret_cast<const float4*>(cb + (size_t)k0 * 64);
        float a0 = 0.f, a1 = 0.f, a2 = 0.f, a3 = 0.f;
        #pragma unroll
        for (int j = 0; j < 16; ++j) {
            const float4 zv = zr[j];
            const float4 c0 = c4[j];
            const float4 c1 = c4[j + 16];
            const float4 c2 = c4[j + 32];
            const float4 c3 = c4[j + 48];
            a0 = fmaf(zv.x, c0.x, a0); a0 = fmaf(zv.y, c0.y, a0);
            a0 = fmaf(zv.z, c0.z, a0); a0 = fmaf(zv.w, c0.w, a0);
            a1 = fmaf(zv.x, c1.x, a1); a1 = fmaf(zv.y, c1.y, a1);
            a1 = fmaf(zv.z, c1.z, a1); a1 = fmaf(zv.w, c1.w, a1);
            a2 = fmaf(zv.x, c2.x, a2); a2 = fmaf(zv.y, c2.y, a2);
            a2 = fmaf(zv.z, c2.z, a2); a2 = fmaf(zv.w, c2.w, a2);
            a3 = fmaf(zv.x, c3.x, a3); a3 = fmaf(zv.y, c3.y, a3);
            a3 = fmaf(zv.z, c3.z, a3); a3 = fmaf(zv.w, c3.w, a3);
        }
        const float d0 = zz + cc[k0    ] - 2.f * a0;
        const float d1 = zz + cc[k0 + 1] - 2.f * a1;
        const float d2 = zz + cc[k0 + 2] - 2.f * a2;
        const float d3 = zz + cc[k0 + 3] - 2.f * a3;
        if (d0 < bestd) { bestd = d0; bestk = k0;     }
        if (d1 < bestd) { bestd = d1; bestk = k0 + 1; }
        if (d2 < bestd) { bestd = d2; bestk = k0 + 2; }
        if (d3 < bestd) { bestd = d3; bestk = k0 + 3; }
    }

    __shared__ float s_dist[8][64];
    __shared__ int   s_idx [8][64];
    __shared__ int   s_final[64];
    s_dist[wid][lane] = bestd;
    s_idx [wid][lane] = bestk;
    __syncthreads();

    if (wid == 0) {
        float bd = s_dist[0][lane];
        int   bk = s_idx [0][lane];
        #pragma unroll
        for (int w = 1; w < 8; ++w) {
            const float dw = s_dist[w][lane];
            if (dw < bd) { bd = dw; bk = s_idx[w][lane]; }  // strict <: first-index tiebreak
        }
        s_final[lane] = bk;
        out[OFF_IDX + row] = (float)bk;
        atomicAdd(&out[OFF_NECS + bk], 1.0f);               // cluster count
    }
    __syncthreads();

    // Phase 2: coalesced z_q write + commitment SSE + cluster-sum atomics.
    // Block tile = 64 rows * 64 dims = 1024 float4s; thread t handles 2.
    const int t = threadIdx.x;
    float sse = 0.f;
    const float4* zb = reinterpret_cast<const float4*>(z) + (size_t)blockIdx.x * 1024;
    float4*       qb = reinterpret_cast<float4*>(out + OFF_ZQ) + (size_t)blockIdx.x * 1024;
    const float4* cb4 = reinterpret_cast<const float4*>(cb);
    #pragma unroll
    for (int j = 0; j < 2; ++j) {
        const int f  = t + 512 * j;     // float4 index in block tile
        const int r  = f >> 4;          // row within tile
        const int fc = f & 15;          // float4 within row
        const int gk = s_final[r];
        const float4 zv = zb[f];
        const float4 cv = cb4[gk * 16 + fc];
        qb[f] = cv;                     // z_q_st == z_q numerically
        const float e0 = zv.x - cv.x, e1 = zv.y - cv.y;
        const float e2 = zv.z - cv.z, e3 = zv.w - cv.w;
        sse += e0*e0 + e1*e1 + e2*e2 + e3*e3;
        float* sp = out + OFF_NEW + gk * 64 + fc * 4;
        atomicAdd(sp + 0, zv.x);
        atomicAdd(sp + 1, zv.y);
        atomicAdd(sp + 2, zv.z);
        atomicAdd(sp + 3, zv.w);
    }

    __shared__ float s_red[512];
    s_red[t] = sse;
    __syncthreads();
    for (int off = 256; off > 0; off >>= 1) {
        if (t < off) s_red[t] += s_red[t + off];
        __syncthreads();
    }
    if (t == 0) atomicAdd(&out[OFF_LOSS], s_red[0]);
}

// One block, 1024 threads: EMA update + normalization + loss finalize.
__global__ __launch_bounds__(1024) void vq_final(const float* __restrict__ ema_cs,
                                                 const float* __restrict__ ema_w,
                                                 float* __restrict__ out) {
    const int k = threadIdx.x;
    const float cnt  = out[OFF_NECS + k];
    const float necs = DECAY * ema_cs[k] + ONEM * cnt;

    __shared__ float s_red[1024];
    __shared__ float s_den[1024];
    s_red[k] = necs;
    __syncthreads();
    for (int off = 512; off > 0; off >>= 1) {
        if (k < off) s_red[k] += s_red[k + off];
        __syncthreads();
    }
    const float n = s_red[0];

    out[OFF_NECS + k] = necs;
    s_den[k] = (necs + EPSV) / (n + (float)KC * EPSV) * n;
    __syncthreads();

    #pragma unroll 4
    for (int i = 0; i < 64; ++i) {
        const int e = k + 1024 * i;             // coalesced over 65536 elements
        const float s  = out[OFF_NEW + e];      // raw cluster sum
        const float ew = DECAY * ema_w[e] + ONEM * s;
        out[OFF_NEW + e] = ew;                  // new_ew
        out[OFF_NCB + e] = ew / s_den[e >> 6];  // new_codebook
    }
    if (k == 0) out[OFF_LOSS] = 0.25f * out[OFF_LOSS] * (1.f / 4194304.f);
}

extern "C" void kernel_launch(void* const* d_in, const int* in_sizes, int n_in,
                              void* d_out, int out_size, void* d_ws, size_t ws_size,
                              hipStream_t stream) {
    const float* z   = (const float*)d_in[0];
    const float* cb  = (const float*)d_in[1];
    const float* ecs = (const float*)d_in[2];
    const float* ew  = (const float*)d_in[3];
    float* out = (float*)d_out;

    vq_prep <<<256,  256, 0, stream>>>(cb, out);
    vq_main <<<1024, 512, 0, stream>>>(z, cb, out + OFF_NCB, out);
    vq_final<<<1,   1024, 0, stream>>>(ecs, ew, out);
}

// Round 3
// 297.994 us; speedup vs baseline: 1.0939x; 1.0601x over previous
//
#include <hip/hip_runtime.h>

// Problem constants
#define KC   1024        // codebook size
#define DD   64          // code dim
#define NR   65536       // total rows (16*4096)

#define DECAY     0.99f
#define ONEM      0.01f
#define EPSV      1e-5f

// d_out layout (floats), in reference return order:
#define OFF_ZQ    0
#define OFF_LOSS  4194304
#define OFF_IDX   4194305
#define OFF_NCB   4259841
#define OFF_NECS  4325377
#define OFF_NEW   4326401

// Scratch aliases inside d_out (zeroed by prep, consumed+overwritten by final):
//   cluster counts  -> OFF_NECS region (1024)
//   cluster sums    -> OFF_NEW region (65536)
//   sum-sq-error    -> OFF_LOSS (1)
//   ||c||^2 table   -> first 1024 floats of OFF_NCB region

__global__ void vq_prep(const float* __restrict__ cb, float* __restrict__ out) {
    int tid = blockIdx.x * blockDim.x + threadIdx.x;
    if (tid < 65536) out[OFF_NEW + tid] = 0.0f;          // cluster sums
    if (tid < 1024) {
        out[OFF_NECS + tid] = 0.0f;                      // cluster counts
        const float* c = cb + tid * 64;
        float s = 0.f;
        #pragma unroll
        for (int d = 0; d < 64; ++d) s += c[d] * c[d];
        out[OFF_NCB + tid] = s;                          // ||c_k||^2
    }
    if (tid == 0) out[OFF_LOSS] = 0.0f;                  // SSE accumulator
}

// 1024 blocks x 512 threads (8 waves). Each block owns 64 rows.
// lane (0..63) = row within block tile; wave (0..7) = 128-code K-chunk.
// Codebook addresses are wave-uniform -> scalar (s_load) broadcast.
// z row is PINNED into 64 VGPRs via opaque asm so the compiler cannot
// rematerialize the global loads inside the k-loop (round-1/2 failure mode:
// VGPR_Count=44, FETCH_SIZE=11GB from per-iteration z re-reads).
__global__ __launch_bounds__(512, 4) void vq_main(const float* __restrict__ z,
                                                  const float* __restrict__ cb,
                                                  const float* __restrict__ cc,
                                                  float* __restrict__ out) {
    const int lane = threadIdx.x & 63;
    const int wid  = threadIdx.x >> 6;
    const int row  = blockIdx.x * 64 + lane;

    // Load this lane's z row into registers.
    float zr[64];
    {
        const float4* zp = reinterpret_cast<const float4*>(z + (size_t)row * 64);
        #pragma unroll
        for (int j = 0; j < 16; ++j) {
            float4 v = zp[j];
            zr[4*j+0] = v.x; zr[4*j+1] = v.y; zr[4*j+2] = v.z; zr[4*j+3] = v.w;
        }
    }
    // Pin: force all 64 values into live VGPRs; no remat possible after this.
    #pragma unroll
    for (int j = 0; j < 64; j += 8)
        asm volatile("" : "+v"(zr[j+0]), "+v"(zr[j+1]), "+v"(zr[j+2]), "+v"(zr[j+3]),
                          "+v"(zr[j+4]), "+v"(zr[j+5]), "+v"(zr[j+6]), "+v"(zr[j+7]));

    float zz = 0.f;
    #pragma unroll
    for (int d = 0; d < 64; ++d) zz = fmaf(zr[d], zr[d], zz);

    // Wave-uniform chunk base in an SGPR.
    const int kbase = __builtin_amdgcn_readfirstlane(wid) * 128;

    float bestd = 3.4e38f;
    int   bestk = kbase;
    for (int k0 = kbase; k0 < kbase + 128; k0 += 4) {
        const float* c0 = cb + (size_t)k0 * 64;
        float a0 = 0.f, a1 = 0.f, a2 = 0.f, a3 = 0.f;
        #pragma unroll
        for (int d = 0; d < 64; ++d) {
            const float zd = zr[d];
            a0 = fmaf(zd, c0[d      ], a0);
            a1 = fmaf(zd, c0[d +  64], a1);
            a2 = fmaf(zd, c0[d + 128], a2);
            a3 = fmaf(zd, c0[d + 192], a3);
        }
        const float d0 = zz + cc[k0    ] - 2.f * a0;
        const float d1 = zz + cc[k0 + 1] - 2.f * a1;
        const float d2 = zz + cc[k0 + 2] - 2.f * a2;
        const float d3 = zz + cc[k0 + 3] - 2.f * a3;
        if (d0 < bestd) { bestd = d0; bestk = k0;     }
        if (d1 < bestd) { bestd = d1; bestk = k0 + 1; }
        if (d2 < bestd) { bestd = d2; bestk = k0 + 2; }
        if (d3 < bestd) { bestd = d3; bestk = k0 + 3; }
    }

    __shared__ float s_dist[8][64];
    __shared__ int   s_idx [8][64];
    __shared__ int   s_final[64];
    s_dist[wid][lane] = bestd;
    s_idx [wid][lane] = bestk;
    __syncthreads();

    if (wid == 0) {
        float bd = s_dist[0][lane];
        int   bk = s_idx [0][lane];
        #pragma unroll
        for (int w = 1; w < 8; ++w) {
            const float dw = s_dist[w][lane];
            if (dw < bd) { bd = dw; bk = s_idx[w][lane]; }  // strict <: first-index tiebreak
        }
        s_final[lane] = bk;
        out[OFF_IDX + row] = (float)bk;
        atomicAdd(&out[OFF_NECS + bk], 1.0f);               // cluster count
    }
    __syncthreads();

    // Phase 2: coalesced z_q write + commitment SSE + cluster-sum atomics.
    // Block tile = 64 rows * 64 dims = 1024 float4s; thread t handles 2.
    const int t = threadIdx.x;
    float sse = 0.f;
    const float4* zb = reinterpret_cast<const float4*>(z) + (size_t)blockIdx.x * 1024;
    float4*       qb = reinterpret_cast<float4*>(out + OFF_ZQ) + (size_t)blockIdx.x * 1024;
    const float4* cb4 = reinterpret_cast<const float4*>(cb);
    #pragma unroll
    for (int j = 0; j < 2; ++j) {
        const int f  = t + 512 * j;     // float4 index in block tile
        const int r  = f >> 4;          // row within tile
        const int fc = f & 15;          // float4 within row
        const int gk = s_final[r];
        const float4 zv = zb[f];
        const float4 cv = cb4[gk * 16 + fc];
        qb[f] = cv;                     // z_q_st == z_q numerically
        const float e0 = zv.x - cv.x, e1 = zv.y - cv.y;
        const float e2 = zv.z - cv.z, e3 = zv.w - cv.w;
        sse += e0*e0 + e1*e1 + e2*e2 + e3*e3;
        float* sp = out + OFF_NEW + gk * 64 + fc * 4;
        atomicAdd(sp + 0, zv.x);
        atomicAdd(sp + 1, zv.y);
        atomicAdd(sp + 2, zv.z);
        atomicAdd(sp + 3, zv.w);
    }

    __shared__ float s_red[512];
    s_red[t] = sse;
    __syncthreads();
    for (int off = 256; off > 0; off >>= 1) {
        if (t < off) s_red[t] += s_red[t + off];
        __syncthreads();
    }
    if (t == 0) atomicAdd(&out[OFF_LOSS], s_red[0]);
}

// One block, 1024 threads: EMA update + normalization + loss finalize.
__global__ __launch_bounds__(1024) void vq_final(const float* __restrict__ ema_cs,
                                                 const float* __restrict__ ema_w,
                                                 float* __restrict__ out) {
    const int k = threadIdx.x;
    const float cnt  = out[OFF_NECS + k];
    const float necs = DECAY * ema_cs[k] + ONEM * cnt;

    __shared__ float s_red[1024];
    __shared__ float s_den[1024];
    s_red[k] = necs;
    __syncthreads();
    for (int off = 512; off > 0; off >>= 1) {
        if (k < off) s_red[k] += s_red[k + off];
        __syncthreads();
    }
    const float n = s_red[0];

    out[OFF_NECS + k] = necs;
    s_den[k] = (necs + EPSV) / (n + (float)KC * EPSV) * n;
    __syncthreads();

    #pragma unroll 4
    for (int i = 0; i < 64; ++i) {
        const int e = k + 1024 * i;             // coalesced over 65536 elements
        const float s  = out[OFF_NEW + e];      // raw cluster sum
        const float ew = DECAY * ema_w[e] + ONEM * s;
        out[OFF_NEW + e] = ew;                  // new_ew
        out[OFF_NCB + e] = ew / s_den[e >> 6];  // new_codebook
    }
    if (k == 0) out[OFF_LOSS] = 0.25f * out[OFF_LOSS] * (1.f / 4194304.f);
}

extern "C" void kernel_launch(void* const* d_in, const int* in_sizes, int n_in,
                              void* d_out, int out_size, void* d_ws, size_t ws_size,
                              hipStream_t stream) {
    const float* z   = (const float*)d_in[0];
    const float* cb  = (const float*)d_in[1];
    const float* ecs = (const float*)d_in[2];
    const float* ew  = (const float*)d_in[3];
    float* out = (float*)d_out;

    vq_prep <<<256,  256, 0, stream>>>(cb, out);
    vq_main <<<1024, 512, 0, stream>>>(z, cb, out + OFF_NCB, out);
    vq_final<<<1,   1024, 0, stream>>>(ecs, ew, out);
}